// Round 4
// baseline (256.069 us; speedup 1.0000x reference)
//
#include <hip/hip_runtime.h>

#define SS 128
#define RR 128
#define CC 128
#define RC (RR * CC)
#define LS 8            // s-planes per block
#define EPSF 1e-14f

// Block = 256 threads = 8 rows x 32 float4-cols, iterating LS s-planes.
// s-diff from register rotation; r-diff from global re-read (cache hit);
// c-diff via shfl. Boundaries by 0/1 weights with clamped offsets.
__global__ __launch_bounds__(256, 2) void scol_main(const float* __restrict__ L,
                                                    const float* __restrict__ U,
                                                    float4* __restrict__ part,
                                                    int sChunks, int rChunks) {
    const int SRC = SS * RC;

    int tid  = threadIdx.x;
    int c4   = tid & 31;
    int rblk = tid >> 5;

    int g   = blockIdx.x;
    int sc  = g % sChunks;
    int rc  = (g / sChunks) % rChunks;
    int b   = g / (sChunks * rChunks);

    int r  = rc * 8 + rblk;
    int s0 = sc * LS;
    int c  = c4 << 2;

    bool  hr = (r < RR - 1), hc = (c4 < 31);
    float wr = hr ? 1.f : 0.f;
    float wc = hc ? 1.f : 0.f;
    int offr = hr ? CC : 0;

    int pos    = (s0 * RR + r) * CC + c;
    int base_l = b * 3 * SRC;
    int base_u = b * 9 * SRC;

    // ---- prologue: u_cur = U(s0) ----
    float4 ucur[9];
#pragma unroll
    for (int ch = 0; ch < 9; ++ch)
        ucur[ch] = *(const float4*)(U + base_u + ch * SRC + pos);

    float a_co = 0.f, a_ds = 0.f, a_dr = 0.f, a_dc = 0.f;

#pragma unroll 2
    for (int i = 0; i < LS; ++i) {
        int s = s0 + i;
        bool  hs  = (s < SS - 1);
        float wsf = hs ? 1.f : 0.f;
        int offn  = hs ? RC : 0;     // next plane (clamped at global end)

        // ---- issue all loads for this step: 3 L + 9 ur + 9 unext ----
        float4 l0 = *(const float4*)(L + base_l + pos);
        float4 l1 = *(const float4*)(L + base_l + SRC + pos);
        float4 l2 = *(const float4*)(L + base_l + 2 * SRC + pos);

        float4 urv[9], unx[9];
#pragma unroll
        for (int ch = 0; ch < 9; ++ch) {
            const float* p = U + base_u + ch * SRC + pos;
            urv[ch] = *(const float4*)(p + offr);
            unx[ch] = *(const float4*)(p + offn);
        }

        // ---- argmax over L channels ----
        float L0[4] = {l0.x, l0.y, l0.z, l0.w};
        float L1[4] = {l1.x, l1.y, l1.z, l1.w};
        float L2[4] = {l2.x, l2.y, l2.z, l2.w};
        int idx[4];
#pragma unroll
        for (int j = 0; j < 4; ++j) {
            int id = 0;
            float best = L0[j];
            if (L1[j] > best) { best = L1[j]; id = 1; }
            if (L2[j] > best) { best = L2[j]; id = 2; }
            idx[j] = id;
        }

        float am[3][4];
#pragma unroll
        for (int gi = 0; gi < 3; ++gi)
#pragma unroll
            for (int j = 0; j < 4; ++j) am[gi][j] = 0.f;

        float t_dcb = 0.f, t_dr = 0.f, t_ds = 0.f;

#pragma unroll
        for (int ch = 0; ch < 9; ++ch) {
            float4 uu = ucur[ch];
            float uuv[4] = {uu.x, uu.y, uu.z, uu.w};
            int gi = ch / 3, m = ch % 3;
#pragma unroll
            for (int j = 0; j < 4; ++j)
                if (idx[j] == m) am[gi][j] = fabsf(uuv[j]);

            float d;
            d = uu.y - uu.x; a_dc += d * d;
            d = uu.z - uu.y; a_dc += d * d;
            d = uu.w - uu.z; a_dc += d * d;
            float un1 = __shfl_down(uu.x, 1);
            d = un1 - uu.w; t_dcb += d * d;

            float4 R4 = urv[ch];
            d = R4.x - uu.x; t_dr += d * d;
            d = R4.y - uu.y; t_dr += d * d;
            d = R4.z - uu.z; t_dr += d * d;
            d = R4.w - uu.w; t_dr += d * d;

            float4 S4 = unx[ch];
            d = S4.x - uu.x; t_ds += d * d;
            d = S4.y - uu.y; t_ds += d * d;
            d = S4.z - uu.z; t_ds += d * d;
            d = S4.w - uu.w; t_ds += d * d;

            ucur[ch] = S4;   // rotate: next plane becomes current
        }
        a_dc += wc * t_dcb;
        a_dr += wr * t_dr;
        a_ds += wsf * t_ds;

#pragma unroll
        for (int j = 0; j < 4; ++j) {
            float e1 = am[0][j], e2 = am[1][j], e3 = am[2][j];
            float den = e1 * e1 + e2 * e2 + e3 * e3;
            den = fmaxf(den, EPSF);
            float num = 0.5f * ((e1 - e2) * (e1 - e2) + (e2 - e3) * (e2 - e3) +
                                (e3 - e1) * (e3 - e1));
            a_co += sqrtf(num / den);
        }

        pos += RC;
    }

    // ---- wave reduce (64 lanes) ----
#pragma unroll
    for (int off = 32; off > 0; off >>= 1) {
        a_co += __shfl_down(a_co, off);
        a_ds += __shfl_down(a_ds, off);
        a_dr += __shfl_down(a_dr, off);
        a_dc += __shfl_down(a_dc, off);
    }

    __shared__ float s_co[4], s_ds[4], s_dr[4], s_dc[4];
    int wid  = threadIdx.x >> 6;
    int lane = threadIdx.x & 63;
    if (lane == 0) {
        s_co[wid] = a_co; s_ds[wid] = a_ds;
        s_dr[wid] = a_dr; s_dc[wid] = a_dc;
    }
    __syncthreads();
    if (threadIdx.x == 0) {
        float t_co = 0.f, t_s = 0.f, t_r = 0.f, t_c = 0.f;
        for (int w = 0; w < 4; ++w) {
            t_co += s_co[w]; t_s += s_ds[w];
            t_r += s_dr[w]; t_c += s_dc[w];
        }
        part[blockIdx.x] = make_float4(t_co, t_s, t_r, t_c);
    }
}

// Single block: reduce nblk float4 partials in double, emit the scalar.
__global__ __launch_bounds__(256) void scol_final(const float4* __restrict__ part,
                                                  float* __restrict__ out,
                                                  int nblk, int B) {
    double d_co = 0., d_ds = 0., d_dr = 0., d_dc = 0.;
    for (int i = threadIdx.x; i < nblk; i += blockDim.x) {
        float4 p = part[i];
        d_co += (double)p.x; d_ds += (double)p.y;
        d_dr += (double)p.z; d_dc += (double)p.w;
    }
#pragma unroll
    for (int off = 32; off > 0; off >>= 1) {
        d_co += __shfl_down(d_co, off);
        d_ds += __shfl_down(d_ds, off);
        d_dr += __shfl_down(d_dr, off);
        d_dc += __shfl_down(d_dc, off);
    }
    __shared__ double sh[4][4];
    int wid  = threadIdx.x >> 6;
    int lane = threadIdx.x & 63;
    if (lane == 0) {
        sh[wid][0] = d_co; sh[wid][1] = d_ds;
        sh[wid][2] = d_dr; sh[wid][3] = d_dc;
    }
    __syncthreads();
    if (threadIdx.x == 0) {
        double t_co = 0., t_ds = 0., t_dr = 0., t_dc = 0.;
        for (int w = 0; w < 4; ++w) {
            t_co += sh[w][0]; t_ds += sh[w][1];
            t_dr += sh[w][2]; t_dc += sh[w][3];
        }
        double nvox = (double)B * SS * RR * CC;
        double nds  = (double)B * (SS - 1) * RR * CC;
        double ndr  = (double)B * SS * (RR - 1) * CC;
        double ndc  = (double)B * SS * RR * (CC - 1);
        out[0] = (float)(0.5 * (t_co / nvox + t_ds / nds + t_dr / ndr + t_dc / ndc));
    }
}

extern "C" void kernel_launch(void* const* d_in, const int* in_sizes, int n_in,
                              void* d_out, int out_size, void* d_ws, size_t ws_size,
                              hipStream_t stream) {
    const float* L = (const float*)d_in[0];
    const float* U = (const float*)d_in[1];
    float* out = (float*)d_out;

    int B = in_sizes[1] / (9 * SS * RR * CC);
    int sChunks = SS / LS;        // 16
    int rChunks = RR / 8;         // 16
    int blocks  = B * sChunks * rChunks;   // 512 for B=2

    float4* part = (float4*)d_ws;

    hipLaunchKernelGGL(scol_main, dim3(blocks), dim3(256), 0, stream,
                       L, U, part, sChunks, rChunks);
    hipLaunchKernelGGL(scol_final, dim3(1), dim3(256), 0, stream,
                       part, out, blocks, B);
}